// Round 6
// baseline (162.988 us; speedup 1.0000x reference)
//
#include <hip/hip_runtime.h>
#include <hip/hip_bf16.h>

#define B_      16
#define N_      1024
#define ALPHA_  0.2f
#define LOG2E_  1.4426950408889634f

typedef __attribute__((ext_vector_type(8)))  __bf16 bf16x8;
typedef __attribute__((ext_vector_type(4)))  float  floatx4;
typedef __attribute__((ext_vector_type(16))) float  floatx16;

__device__ __forceinline__ float eluf(float u) { return u > 0.f ? u : __expf(u) - 1.f; }

__device__ __forceinline__ float exp2fast(float x) {
#if __has_builtin(__builtin_amdgcn_exp2f)
    return __builtin_amdgcn_exp2f(x);
#else
    return exp2f(x);
#endif
}

__device__ __forceinline__ floatx4 mfma_bf16(bf16x8 a, bf16x8 b, floatx4 c) {
    return __builtin_amdgcn_mfma_f32_16x16x32_bf16(a, b, c, 0, 0, 0);
}
__device__ __forceinline__ floatx16 mfma32_bf16(bf16x8 a, bf16x8 b, floatx16 c) {
    return __builtin_amdgcn_mfma_f32_32x32x16_bf16(a, b, c, 0, 0, 0);
}

// ---------------------------------------------------------------------------
// proj1 (MFMA): h = x[b,n0:n0+64,:64] @ (n0<512 ? W1[head] : W2[head])
// writes h1t[(head*16+b)*64 + d][m] bf16 (transposed) + A1/A2 fp32 dots
// (pre-scaled by log2e for exp2 consumers). Also folds maskbits conversion.
__global__ __launch_bounds__(256) void proj1_kernel(
    const float* __restrict__ x, const float* __restrict__ W1,
    const float* __restrict__ W2, const float* __restrict__ av,
    const float* __restrict__ maskG, unsigned* __restrict__ bitsOut,
    __bf16* __restrict__ h1t, float* __restrict__ A1, float* __restrict__ A2)
{
    const int tile = blockIdx.x, b = blockIdx.y, head = blockIdx.z;
    const int n0 = tile * 64;
    const float* W  = ((n0 < 512) ? W1 : W2) + head * 64 * 64;
    const float* ah = av + head * 128;

    __shared__ __align__(16) __bf16 xs[64][72];
    __shared__ __align__(16) __bf16 Wt[64][72];
    __shared__ __align__(16) float as_[128];

    const int tid = threadIdx.x;
    if (tid < 128) as_[tid] = ah[tid];
#pragma unroll
    for (int i = 0; i < 4; ++i) {
        int idx = i * 256 + tid;
        int r = idx >> 4, c = (idx & 15) * 4;
        float4 v = *(const float4*)(x + ((size_t)(b * N_ + n0 + r)) * 64 + c);
        xs[r][c+0] = (__bf16)v.x; xs[r][c+1] = (__bf16)v.y;
        xs[r][c+2] = (__bf16)v.z; xs[r][c+3] = (__bf16)v.w;
        float4 wv = *(const float4*)(W + (size_t)r * 64 + c);
        Wt[c+0][r] = (__bf16)wv.x; Wt[c+1][r] = (__bf16)wv.y;
        Wt[c+2][r] = (__bf16)wv.z; Wt[c+3][r] = (__bf16)wv.w;
    }

    // fused maskbits: this block converts its 32 words (1024 mask floats)
    {
        const int bid = blockIdx.x + 16 * (blockIdx.y + 16 * blockIdx.z);
        if (tid < 32) {
            const float* src = maskG + ((size_t)(bid * 32 + tid)) * 32;
            unsigned v = 0;
#pragma unroll
            for (int j = 0; j < 8; ++j) {
                float4 f = *(const float4*)(src + j * 4);
                v |= ((unsigned)(f.x != 0.f)) << (j * 4 + 0);
                v |= ((unsigned)(f.y != 0.f)) << (j * 4 + 1);
                v |= ((unsigned)(f.z != 0.f)) << (j * 4 + 2);
                v |= ((unsigned)(f.w != 0.f)) << (j * 4 + 3);
            }
            bitsOut[bid * 32 + tid] = v;
        }
    }
    __syncthreads();

    const int w = tid >> 6, L = tid & 63, quad = L >> 4, lo = L & 15;
    floatx4 acc[4] = {{0,0,0,0},{0,0,0,0},{0,0,0,0},{0,0,0,0}};
#pragma unroll
    for (int kc = 0; kc < 2; ++kc) {
        bf16x8 af = *(bf16x8*)&xs[16 * w + lo][kc * 32 + quad * 8];
#pragma unroll
        for (int t = 0; t < 4; ++t) {
            bf16x8 bv = *(bf16x8*)&Wt[16 * t + lo][kc * 32 + quad * 8];
            acc[t] = mfma_bf16(af, bv, acc[t]);
        }
    }

    float p1[4] = {0, 0, 0, 0}, p2[4] = {0, 0, 0, 0};
#pragma unroll
    for (int t = 0; t < 4; ++t) {
        float a1w = as_[16 * t + lo], a2w = as_[64 + 16 * t + lo];
#pragma unroll
        for (int i = 0; i < 4; ++i) { p1[i] += acc[t][i] * a1w; p2[i] += acc[t][i] * a2w; }
    }
#pragma unroll
    for (int s = 1; s < 16; s <<= 1)
#pragma unroll
        for (int i = 0; i < 4; ++i) {
            p1[i] += __shfl_xor(p1[i], s);
            p2[i] += __shfl_xor(p2[i], s);
        }
    const int bh = head * B_ + b;
    if (lo == 0) {
#pragma unroll
        for (int i = 0; i < 4; ++i) {
            int n = 16 * w + quad * 4 + i;
            A1[bh * N_ + n0 + n] = p1[i] * LOG2E_;
            A2[bh * N_ + n0 + n] = p2[i] * LOG2E_;
        }
    }

    __syncthreads();
#pragma unroll
    for (int t = 0; t < 4; ++t)
#pragma unroll
        for (int i = 0; i < 4; ++i)
            xs[16 * w + quad * 4 + i][16 * t + lo] = (__bf16)acc[t][i];
    __syncthreads();
    const int d = tid & 63, ch = tid >> 6;
    bf16x8 v0, v1;
#pragma unroll
    for (int j = 0; j < 8; ++j) v0[j] = xs[ch * 16 + j][d];
#pragma unroll
    for (int j = 0; j < 8; ++j) v1[j] = xs[ch * 16 + 8 + j][d];
    bf16x8* dst = (bf16x8*)(h1t + ((size_t)bh * 64 + d) * N_ + n0 + ch * 16);
    dst[0] = v0; dst[1] = v1;
}

// ---------------------------------------------------------------------------
// attn layer 1 (32x32x16 MFMA): grid (b, head, tile) = (16,4,8), 128-row tiles.
// P computed directly in A-fragment regs. B-fragments loaded DIRECTLY from
// global h1t (16B contiguous per lane) -- the old LDS staging was a pure
// pass-through (each element written/read exactly once), so the main loop is
// now completely barrier-free and LDS-free; waves run as independent streams.
__global__ __launch_bounds__(256) void attn1_kernel(
    const float* __restrict__ A1g, const float* __restrict__ A2g,
    const __bf16* __restrict__ Htg, const unsigned* __restrict__ bitsG,
    __bf16* __restrict__ xc_out)
{
    const int b = blockIdx.x, head = blockIdx.y, tile = blockIdx.z;
    const int n0 = tile * 128;
    const int bh = head * B_ + b;
    const float* A2 = A2g + (size_t)bh * N_;
    const __bf16* Hglob = Htg + (size_t)bh * 64 * N_;

    __shared__ __align__(16) __bf16 ts[128][72];          // epilogue staging
    __shared__ __align__(16) float A2s[N_];
    __shared__ __align__(16) unsigned bitsS[32 * 128];    // [w][row]
    __shared__ float invzS[128];

    const int tid = threadIdx.x;
    *(float4*)&A2s[tid * 4] = *(const float4*)(A2 + tid * 4);
    {   // bits rows n0..n0+127 transposed: src word s=tid*16+k -> row=tid>>1, w=(tid&1)*16+k
        const int row = tid >> 1, w0 = (tid & 1) * 16;
        uint4 u0 = *(const uint4*)(bitsG + n0 * 32 + tid * 16);
        uint4 u1 = *(const uint4*)(bitsG + n0 * 32 + tid * 16 + 4);
        uint4 u2 = *(const uint4*)(bitsG + n0 * 32 + tid * 16 + 8);
        uint4 u3 = *(const uint4*)(bitsG + n0 * 32 + tid * 16 + 12);
        bitsS[(w0+ 0)*128+row] = u0.x; bitsS[(w0+ 1)*128+row] = u0.y;
        bitsS[(w0+ 2)*128+row] = u0.z; bitsS[(w0+ 3)*128+row] = u0.w;
        bitsS[(w0+ 4)*128+row] = u1.x; bitsS[(w0+ 5)*128+row] = u1.y;
        bitsS[(w0+ 6)*128+row] = u1.z; bitsS[(w0+ 7)*128+row] = u1.w;
        bitsS[(w0+ 8)*128+row] = u2.x; bitsS[(w0+ 9)*128+row] = u2.y;
        bitsS[(w0+10)*128+row] = u2.z; bitsS[(w0+11)*128+row] = u2.w;
        bitsS[(w0+12)*128+row] = u3.x; bitsS[(w0+13)*128+row] = u3.y;
        bitsS[(w0+14)*128+row] = u3.z; bitsS[(w0+15)*128+row] = u3.w;
    }

    const int L = tid & 63, rg = tid >> 6, hi = L >> 5, lq = L & 31;
    const int rloc = rg * 32 + lq;                       // this lane's P-row (block-local)
    const float a1r = A1g[(size_t)bh * N_ + n0 + rloc];

    // direct B-fragment base pointers: acc0 covers d=0..31 (row lq),
    // acc1 covers d=32..63 (row lq+32); k-offset = mt*64 + ks*16 + hi*8.
    const __bf16* hb0 = Hglob + (size_t)lq * N_;
    const __bf16* hb1 = Hglob + (size_t)(lq + 32) * N_;

    __syncthreads();   // A2s/bitsS visible; the ONLY pre-loop barrier

    floatx16 acc0 = {0,0,0,0,0,0,0,0,0,0,0,0,0,0,0,0};
    floatx16 acc1 = {0,0,0,0,0,0,0,0,0,0,0,0,0,0,0,0};
    float zacc = 0.f;

    for (int mt = 0; mt < 16; ++mt) {
        bf16x8 bv0[4], bv1[4];
#pragma unroll
        for (int ks = 0; ks < 4; ++ks) {                 // issue all 8 loads up front
            const int mo = mt * 64 + ks * 16 + hi * 8;
            bv0[ks] = *(const bf16x8*)(hb0 + mo);
            bv1[ks] = *(const bf16x8*)(hb1 + mo);
        }
#pragma unroll
        for (int ks = 0; ks < 4; ++ks) {
            const int mbase = mt * 64 + ks * 16 + hi * 8;
            const unsigned wb = bitsS[(mbase >> 5) * 128 + rloc] >> (mbase & 31);
            float4 av  = *(const float4*)&A2s[mbase];
            float4 av2 = *(const float4*)&A2s[mbase + 4];
            float a2v[8] = {av.x, av.y, av.z, av.w, av2.x, av2.y, av2.z, av2.w};
            float o[8];
#pragma unroll
            for (int j = 0; j < 8; ++j) {
                float s = a1r + a2v[j];
                float lr = fmaxf(s, ALPHA_ * s);
                int bm = (int)(wb << (31 - j)) >> 31;        // bit j -> all-ones
                lr = __int_as_float(__float_as_int(lr) & bm); // masked -> 0
                float t = exp2fast(lr);                       // scores pre-scaled by log2e
                zacc += t; o[j] = t;
            }
            bf16x8 af = {(__bf16)o[0], (__bf16)o[1], (__bf16)o[2], (__bf16)o[3],
                         (__bf16)o[4], (__bf16)o[5], (__bf16)o[6], (__bf16)o[7]};
            acc0 = mfma32_bf16(af, bv0[ks], acc0);
            acc1 = mfma32_bf16(af, bv1[ks], acc1);
        }
    }

    // z per row: lane covers half the k's of row rloc; partner is lane^32
    zacc += __shfl_xor(zacc, 32);
    if (hi == 0) invzS[rloc] = 1.f / zacc;
    __syncthreads();

    float iz[16];
#pragma unroll
    for (int r = 0; r < 16; ++r)
        iz[r] = invzS[rg * 32 + (r & 3) + 8 * (r >> 2) + 4 * hi];

#pragma unroll
    for (int r = 0; r < 16; ++r) {
        const int row = rg * 32 + (r & 3) + 8 * (r >> 2) + 4 * hi;
        ts[row][lq]      = (__bf16)eluf(acc0[r] * iz[r]);
        ts[row][32 + lq] = (__bf16)eluf(acc1[r] * iz[r]);
    }
    __syncthreads();
#pragma unroll
    for (int i = 0; i < 4; ++i) {
        int cid = i * 256 + tid;
        int row = cid >> 3, c8 = (cid & 7) * 8;
        bf16x8 v = *(bf16x8*)&ts[row][c8];
        *(bf16x8*)(xc_out + ((size_t)(b * N_ + n0 + row)) * 256 + head * 64 + c8) = v;
    }
}

// ---------------------------------------------------------------------------
// attn layer 2: 32-row tiles, grid (b,1,tile)=(16,1,32).
// B-fragments (h2t) loaded directly from global (pass-through LDS removed);
// ts2 (P redistribution, 4x reuse) stays LDS double-buffered -> 1 barrier/iter.
// tr[16] in regs for the attn tail. exp2 scores.
__global__ __launch_bounds__(256) void attn2_kernel(
    const float* __restrict__ A1g, const float* __restrict__ A2g,
    const __bf16* __restrict__ Htg, const unsigned* __restrict__ bitsG,
    float* __restrict__ out_f, float* __restrict__ attn_f)
{
    const int b = blockIdx.x, tile = blockIdx.z;
    const int n0 = tile * 32;
    const float* A2 = A2g + (size_t)b * N_;
    const __bf16* Hglob = Htg + (size_t)b * 64 * N_;

    __shared__ __align__(16) __bf16 ts2[2][32][72];
    __shared__ __align__(16) float A2s[N_];
    __shared__ __align__(16) unsigned bitsS[1024];   // transposed [w32][row32]
    __shared__ float invz[32];

    const int tid = threadIdx.x;
    *(float4*)&A2s[tid * 4] = *(const float4*)(A2 + tid * 4);
    {   // src word s=tid*4+k -> row=s>>5 (=tid>>3), w=s&31
        uint4 u = *(const uint4*)(bitsG + n0 * 32 + tid * 4);
        const int row = tid >> 3, wb0 = (tid & 7) * 4;
        bitsS[(wb0+0)*32+row] = u.x; bitsS[(wb0+1)*32+row] = u.y;
        bitsS[(wb0+2)*32+row] = u.z; bitsS[(wb0+3)*32+row] = u.w;
    }

    const int r2 = tid >> 3, q2 = tid & 7;          // t-staging: row r2, 8 m's
    const float a1r = A1g[(size_t)b * N_ + n0 + r2];
    const int w = tid >> 6, L = tid & 63, quad = L >> 4, lo = L & 15;
    // direct B-frag: row d = 16w+lo of h2t[b]; k-offset = mt*64 + c*32 + quad*8
    const __bf16* hrow2 = Hglob + (size_t)(16 * w + lo) * N_;

    floatx4 acc2[2] = {{0,0,0,0},{0,0,0,0}};
    float zacc = 0.f;
    bf16x8 tr[16];

    __syncthreads();   // A2s/bitsS visible before scores(0)

    auto scores = [&](int mt) -> bf16x8 {
        const int mb = mt * 64 + q2 * 8;
        const unsigned wb = bitsS[(mt * 2 + (q2 >> 2)) * 32 + r2] >> ((q2 & 3) * 8);
        float4 alo = *(const float4*)&A2s[mb];
        float4 ahi = *(const float4*)&A2s[mb + 4];
        float a2v[8] = {alo.x, alo.y, alo.z, alo.w, ahi.x, ahi.y, ahi.z, ahi.w};
        float o[8];
#pragma unroll
        for (int j = 0; j < 8; ++j) {
            float s = a1r + a2v[j];
            float lr = fmaxf(s, ALPHA_ * s);
            int bm = (int)(wb << (31 - j)) >> 31;
            lr = __int_as_float(__float_as_int(lr) & bm);
            float t = exp2fast(lr);
            zacc += t; o[j] = t;
        }
        bf16x8 pk = {(__bf16)o[0], (__bf16)o[1], (__bf16)o[2], (__bf16)o[3],
                     (__bf16)o[4], (__bf16)o[5], (__bf16)o[6], (__bf16)o[7]};
        return pk;
    };

    {   // prologue: stage P(0)
        bf16x8 pk = scores(0);
        tr[0] = pk;
        *(bf16x8*)&ts2[0][r2][q2 * 8] = pk;
    }
    __syncthreads();

#pragma unroll
    for (int mt = 0; mt < 16; ++mt) {
        const int cur = mt & 1;
        bf16x8 pk;
        if (mt < 15) {
            pk = scores(mt + 1);
            tr[mt + 1] = pk;
        }
        bf16x8 bvc[2];
#pragma unroll
        for (int c = 0; c < 2; ++c)
            bvc[c] = *(const bf16x8*)(hrow2 + mt * 64 + c * 32 + quad * 8);
#pragma unroll
        for (int c = 0; c < 2; ++c)
#pragma unroll
            for (int rt = 0; rt < 2; ++rt) {
                bf16x8 af = *(bf16x8*)&ts2[cur][16 * rt + lo][c * 32 + quad * 8];
                acc2[rt] = mfma_bf16(af, bvc[c], acc2[rt]);
            }
        if (mt < 15) {
            *(bf16x8*)&ts2[cur ^ 1][r2][q2 * 8] = pk;
            __syncthreads();
        }
    }

    zacc += __shfl_xor(zacc, 1);
    zacc += __shfl_xor(zacc, 2);
    zacc += __shfl_xor(zacc, 4);
    if (q2 == 0) invz[r2] = 1.f / zacc;
    __syncthreads();

    // out = elu(acc*invz): wave w owns d cols 16w+lo; rows rt*16+quad*4+i
#pragma unroll
    for (int rt = 0; rt < 2; ++rt)
#pragma unroll
        for (int i = 0; i < 4; ++i) {
            const int n = 16 * rt + quad * 4 + i;
            out_f[((size_t)(b * N_ + n0 + n)) * 64 + 16 * w + lo] =
                eluf(acc2[rt][i] * invz[n]);
        }

    // attn tail from saved t regs
    const float iz = invz[r2];
    float* arow = attn_f + ((size_t)(b * N_ + n0 + r2)) * N_ + q2 * 8;
#pragma unroll
    for (int mt = 0; mt < 16; ++mt) {
        bf16x8 t8 = tr[mt];
        float4 f0 = make_float4((float)t8[0] * iz, (float)t8[1] * iz,
                                (float)t8[2] * iz, (float)t8[3] * iz);
        float4 f1 = make_float4((float)t8[4] * iz, (float)t8[5] * iz,
                                (float)t8[6] * iz, (float)t8[7] * iz);
        *(float4*)(arow + mt * 64)     = f0;
        *(float4*)(arow + mt * 64 + 4) = f1;
    }
}

// ---------------------------------------------------------------------------
// proj2: h2 = xc_bf16 @ (n0<512 ? W1o : W2o) via MFMA (K=256); ao-dots + h2t out.
__global__ __launch_bounds__(256) void proj2_kernel(
    const __bf16* __restrict__ xcb, const float* __restrict__ W1o,
    const float* __restrict__ W2o, const float* __restrict__ ao,
    __bf16* __restrict__ h2t, float* __restrict__ A1o, float* __restrict__ A2o)
{
    const int tile = blockIdx.x, b = blockIdx.y;
    const int n0 = tile * 64;
    const float* W = (n0 < 512) ? W1o : W2o;

    __shared__ __align__(16) __bf16 xs[64][264];
    __shared__ __align__(16) __bf16 Wt[64][264];
    __shared__ __align__(16) float as_[128];

    const int tid = threadIdx.x;
    if (tid < 128) as_[tid] = ao[tid];

#pragma unroll
    for (int i = 0; i < 8; ++i) {
        int idx = i * 256 + tid;
        int row = idx >> 5, c = (idx & 31) * 8;
        *(bf16x8*)&xs[row][c] =
            *(const bf16x8*)(xcb + ((size_t)(b * N_ + n0 + row)) * 256 + c);
    }
#pragma unroll
    for (int i = 0; i < 16; ++i) {
        int idx = i * 256 + tid;
        int k = idx >> 4, n4 = (idx & 15) * 4;
        float4 wv = *(const float4*)(W + (size_t)k * 64 + n4);
        Wt[n4 + 0][k] = (__bf16)wv.x;
        Wt[n4 + 1][k] = (__bf16)wv.y;
        Wt[n4 + 2][k] = (__bf16)wv.z;
        Wt[n4 + 3][k] = (__bf16)wv.w;
    }
    __syncthreads();

    const int w = tid >> 6, L = tid & 63, quad = L >> 4, lo = L & 15;
    floatx4 acc[4] = {{0,0,0,0},{0,0,0,0},{0,0,0,0},{0,0,0,0}};
#pragma unroll
    for (int kc = 0; kc < 8; ++kc) {
        bf16x8 af = *(bf16x8*)&xs[16 * w + lo][kc * 32 + quad * 8];
#pragma unroll
        for (int t = 0; t < 4; ++t) {
            bf16x8 bv = *(bf16x8*)&Wt[16 * t + lo][kc * 32 + quad * 8];
            acc[t] = mfma_bf16(af, bv, acc[t]);
        }
    }

    float p1[4] = {0, 0, 0, 0}, p2[4] = {0, 0, 0, 0};
#pragma unroll
    for (int t = 0; t < 4; ++t) {
        float a1w = as_[16 * t + lo], a2w = as_[64 + 16 * t + lo];
#pragma unroll
        for (int i = 0; i < 4; ++i) { p1[i] += acc[t][i] * a1w; p2[i] += acc[t][i] * a2w; }
    }
#pragma unroll
    for (int s = 1; s < 16; s <<= 1)
#pragma unroll
        for (int i = 0; i < 4; ++i) {
            p1[i] += __shfl_xor(p1[i], s);
            p2[i] += __shfl_xor(p2[i], s);
        }
    if (lo == 0) {
#pragma unroll
        for (int i = 0; i < 4; ++i) {
            int n = 16 * w + quad * 4 + i;
            A1o[b * N_ + n0 + n] = p1[i] * LOG2E_;
            A2o[b * N_ + n0 + n] = p2[i] * LOG2E_;
        }
    }

    __syncthreads();
#pragma unroll
    for (int t = 0; t < 4; ++t)
#pragma unroll
        for (int i = 0; i < 4; ++i)
            xs[16 * w + quad * 4 + i][16 * t + lo] = (__bf16)acc[t][i];
    __syncthreads();
    const int d = tid & 63, ch = tid >> 6;
    bf16x8 v0, v1;
#pragma unroll
    for (int j = 0; j < 8; ++j) v0[j] = xs[ch * 16 + j][d];
#pragma unroll
    for (int j = 0; j < 8; ++j) v1[j] = xs[ch * 16 + 8 + j][d];
    bf16x8* dst = (bf16x8*)(h2t + ((size_t)b * 64 + d) * N_ + n0 + ch * 16);
    dst[0] = v0; dst[1] = v1;
}

// ---------------------------------------------------------------------------
extern "C" void kernel_launch(void* const* d_in, const int* in_sizes, int n_in,
                              void* d_out, int out_size, void* d_ws, size_t ws_size,
                              hipStream_t stream)
{
    const float* x    = (const float*)d_in[0];
    const float* mask = (const float*)d_in[1];
    const float* W1   = (const float*)d_in[2];
    const float* W2   = (const float*)d_in[3];
    const float* a    = (const float*)d_in[4];
    const float* W1o  = (const float*)d_in[5];
    const float* W2o  = (const float*)d_in[6];
    const float* ao   = (const float*)d_in[7];

    float* out      = (float*)d_out;                 // [16,1024,64] fp32
    float* attn_out = out + (size_t)B_ * N_ * 64;    // [16,1024,1024] fp32

    float*    ws    = (float*)d_ws;
    float*    A1    = ws;                       // 65536 f
    float*    A2    = A1 + 65536;               // 65536 f
    float*    A1o   = A2 + 65536;               // 16384 f
    float*    A2o   = A1o + 16384;              // 16384 f
    __bf16*   h1t   = (__bf16*)(A2o + 16384);   // 4*16*64*1024 bf16
    __bf16*   h2t   = h1t + 4194304;            // 16*64*1024 bf16
    __bf16*   xcb   = h2t + 1048576;            // 16*1024*256 bf16
    unsigned* bitsG = (unsigned*)(xcb + 4194304); // 32768 u32

    proj1_kernel<<<dim3(16, 16, 4), 256, 0, stream>>>(x, W1, W2, a, mask, bitsG,
                                                      h1t, A1, A2);
    attn1_kernel<<<dim3(16, 4, 8), 256, 0, stream>>>(A1, A2, h1t, bitsG, xcb);
    proj2_kernel<<<dim3(16, 16, 1), 256, 0, stream>>>(xcb, W1o, W2o, ao, h2t, A1o, A2o);
    attn2_kernel<<<dim3(16, 1, 32), 256, 0, stream>>>(A1o, A2o, h2t, bitsG, out, attn_out);
}

// Round 7
// 153.001 us; speedup vs baseline: 1.0653x; 1.0653x over previous
//
#include <hip/hip_runtime.h>
#include <hip/hip_bf16.h>

#define B_      16
#define N_      1024
#define ALPHA_  0.2f
#define LOG2E_  1.4426950408889634f

typedef __attribute__((ext_vector_type(8)))  __bf16 bf16x8;
typedef __attribute__((ext_vector_type(4)))  float  floatx4;
typedef __attribute__((ext_vector_type(16))) float  floatx16;

__device__ __forceinline__ float eluf(float u) { return u > 0.f ? u : __expf(u) - 1.f; }

__device__ __forceinline__ float exp2fast(float x) {
#if __has_builtin(__builtin_amdgcn_exp2f)
    return __builtin_amdgcn_exp2f(x);
#else
    return exp2f(x);
#endif
}

__device__ __forceinline__ floatx4 mfma_bf16(bf16x8 a, bf16x8 b, floatx4 c) {
    return __builtin_amdgcn_mfma_f32_16x16x32_bf16(a, b, c, 0, 0, 0);
}
__device__ __forceinline__ floatx16 mfma32_bf16(bf16x8 a, bf16x8 b, floatx16 c) {
    return __builtin_amdgcn_mfma_f32_32x32x16_bf16(a, b, c, 0, 0, 0);
}

// ---------------------------------------------------------------------------
// proj1 (MFMA): h = x[b,n0:n0+64,:64] @ (n0<512 ? W1[head] : W2[head])
// writes h1t[(head*16+b)*64 + d][m] bf16 (transposed) + A1/A2 fp32 dots
// (pre-scaled by log2e for exp2 consumers). Also folds maskbits conversion.
__global__ __launch_bounds__(256) void proj1_kernel(
    const float* __restrict__ x, const float* __restrict__ W1,
    const float* __restrict__ W2, const float* __restrict__ av,
    const float* __restrict__ maskG, unsigned* __restrict__ bitsOut,
    __bf16* __restrict__ h1t, float* __restrict__ A1, float* __restrict__ A2)
{
    const int tile = blockIdx.x, b = blockIdx.y, head = blockIdx.z;
    const int n0 = tile * 64;
    const float* W  = ((n0 < 512) ? W1 : W2) + head * 64 * 64;
    const float* ah = av + head * 128;

    __shared__ __align__(16) __bf16 xs[64][72];
    __shared__ __align__(16) __bf16 Wt[64][72];
    __shared__ __align__(16) float as_[128];

    const int tid = threadIdx.x;
    if (tid < 128) as_[tid] = ah[tid];
#pragma unroll
    for (int i = 0; i < 4; ++i) {
        int idx = i * 256 + tid;
        int r = idx >> 4, c = (idx & 15) * 4;
        float4 v = *(const float4*)(x + ((size_t)(b * N_ + n0 + r)) * 64 + c);
        xs[r][c+0] = (__bf16)v.x; xs[r][c+1] = (__bf16)v.y;
        xs[r][c+2] = (__bf16)v.z; xs[r][c+3] = (__bf16)v.w;
        float4 wv = *(const float4*)(W + (size_t)r * 64 + c);
        Wt[c+0][r] = (__bf16)wv.x; Wt[c+1][r] = (__bf16)wv.y;
        Wt[c+2][r] = (__bf16)wv.z; Wt[c+3][r] = (__bf16)wv.w;
    }

    // fused maskbits: this block converts its 32 words (1024 mask floats)
    {
        const int bid = blockIdx.x + 16 * (blockIdx.y + 16 * blockIdx.z);
        if (tid < 32) {
            const float* src = maskG + ((size_t)(bid * 32 + tid)) * 32;
            unsigned v = 0;
#pragma unroll
            for (int j = 0; j < 8; ++j) {
                float4 f = *(const float4*)(src + j * 4);
                v |= ((unsigned)(f.x != 0.f)) << (j * 4 + 0);
                v |= ((unsigned)(f.y != 0.f)) << (j * 4 + 1);
                v |= ((unsigned)(f.z != 0.f)) << (j * 4 + 2);
                v |= ((unsigned)(f.w != 0.f)) << (j * 4 + 3);
            }
            bitsOut[bid * 32 + tid] = v;
        }
    }
    __syncthreads();

    const int w = tid >> 6, L = tid & 63, quad = L >> 4, lo = L & 15;
    floatx4 acc[4] = {{0,0,0,0},{0,0,0,0},{0,0,0,0},{0,0,0,0}};
#pragma unroll
    for (int kc = 0; kc < 2; ++kc) {
        bf16x8 af = *(bf16x8*)&xs[16 * w + lo][kc * 32 + quad * 8];
#pragma unroll
        for (int t = 0; t < 4; ++t) {
            bf16x8 bv = *(bf16x8*)&Wt[16 * t + lo][kc * 32 + quad * 8];
            acc[t] = mfma_bf16(af, bv, acc[t]);
        }
    }

    float p1[4] = {0, 0, 0, 0}, p2[4] = {0, 0, 0, 0};
#pragma unroll
    for (int t = 0; t < 4; ++t) {
        float a1w = as_[16 * t + lo], a2w = as_[64 + 16 * t + lo];
#pragma unroll
        for (int i = 0; i < 4; ++i) { p1[i] += acc[t][i] * a1w; p2[i] += acc[t][i] * a2w; }
    }
#pragma unroll
    for (int s = 1; s < 16; s <<= 1)
#pragma unroll
        for (int i = 0; i < 4; ++i) {
            p1[i] += __shfl_xor(p1[i], s);
            p2[i] += __shfl_xor(p2[i], s);
        }
    const int bh = head * B_ + b;
    if (lo == 0) {
#pragma unroll
        for (int i = 0; i < 4; ++i) {
            int n = 16 * w + quad * 4 + i;
            A1[bh * N_ + n0 + n] = p1[i] * LOG2E_;
            A2[bh * N_ + n0 + n] = p2[i] * LOG2E_;
        }
    }

    __syncthreads();
#pragma unroll
    for (int t = 0; t < 4; ++t)
#pragma unroll
        for (int i = 0; i < 4; ++i)
            xs[16 * w + quad * 4 + i][16 * t + lo] = (__bf16)acc[t][i];
    __syncthreads();
    const int d = tid & 63, ch = tid >> 6;
    bf16x8 v0, v1;
#pragma unroll
    for (int j = 0; j < 8; ++j) v0[j] = xs[ch * 16 + j][d];
#pragma unroll
    for (int j = 0; j < 8; ++j) v1[j] = xs[ch * 16 + 8 + j][d];
    bf16x8* dst = (bf16x8*)(h1t + ((size_t)bh * 64 + d) * N_ + n0 + ch * 16);
    dst[0] = v0; dst[1] = v1;
}

// ---------------------------------------------------------------------------
// attn layer 1 (32x32x16 MFMA): grid (b, head, tile) = (16,4,8), 128-row tiles.
// P computed directly in A-fragment regs (zero LDS for P). H^T staged
// pre-fragmented in LDS (coalesced global reads -> conflict-free ds_read_b128).
// frag (loop-only, 16KB) aliased into ts (epilogue-only, 18.4KB), typed overlay
// -> 39.4KB LDS; __launch_bounds__(256,3) -> 3 blocks/CU (VGPR cap 168, no spill).
__global__ __launch_bounds__(256, 3) void attn1_kernel(
    const float* __restrict__ A1g, const float* __restrict__ A2g,
    const __bf16* __restrict__ Htg, const unsigned* __restrict__ bitsG,
    __bf16* __restrict__ xc_out)
{
    const int b = blockIdx.x, head = blockIdx.y, tile = blockIdx.z;
    const int n0 = tile * 128;
    const int bh = head * B_ + b;
    const float* A2 = A2g + (size_t)bh * N_;
    const __bf16* Hglob = Htg + (size_t)bh * 64 * N_;

    __shared__ __align__(16) __bf16 pool[128][72];        // ts (epilogue) = pool
    __bf16 (*frag)[4][2][64][8] = (__bf16(*)[4][2][64][8])&pool[0][0]; // 16KB ⊂ pool
    __shared__ __align__(16) float A2s[N_];
    __shared__ __align__(16) unsigned bitsS[32 * 128];    // [w][row]
    __shared__ float invzS[128];

    const int tid = threadIdx.x;
    *(float4*)&A2s[tid * 4] = *(const float4*)(A2 + tid * 4);
    {   // bits rows n0..n0+127 transposed: src word s=tid*16+k -> row=tid>>1, w=(tid&1)*16+k
        const int row = tid >> 1, w0 = (tid & 1) * 16;
        uint4 u0 = *(const uint4*)(bitsG + n0 * 32 + tid * 16);
        uint4 u1 = *(const uint4*)(bitsG + n0 * 32 + tid * 16 + 4);
        uint4 u2 = *(const uint4*)(bitsG + n0 * 32 + tid * 16 + 8);
        uint4 u3 = *(const uint4*)(bitsG + n0 * 32 + tid * 16 + 12);
        bitsS[(w0+ 0)*128+row] = u0.x; bitsS[(w0+ 1)*128+row] = u0.y;
        bitsS[(w0+ 2)*128+row] = u0.z; bitsS[(w0+ 3)*128+row] = u0.w;
        bitsS[(w0+ 4)*128+row] = u1.x; bitsS[(w0+ 5)*128+row] = u1.y;
        bitsS[(w0+ 6)*128+row] = u1.z; bitsS[(w0+ 7)*128+row] = u1.w;
        bitsS[(w0+ 8)*128+row] = u2.x; bitsS[(w0+ 9)*128+row] = u2.y;
        bitsS[(w0+10)*128+row] = u2.z; bitsS[(w0+11)*128+row] = u2.w;
        bitsS[(w0+12)*128+row] = u3.x; bitsS[(w0+13)*128+row] = u3.y;
        bitsS[(w0+14)*128+row] = u3.z; bitsS[(w0+15)*128+row] = u3.w;
    }

    const int sd = tid >> 2, sq = tid & 3;               // staging: row d, 16-k window
    const __bf16* hrow = Hglob + (size_t)sd * N_ + sq * 16;
    const int L = tid & 63, rg = tid >> 6, hi = L >> 5, lq = L & 31;
    const int rloc = rg * 32 + lq;                       // this lane's P-row (block-local)
    const float a1r = A1g[(size_t)bh * N_ + n0 + rloc];

    // prologue: stage mt=0 (barrier also covers A2s/bitsS)
    bf16x8 h0 = *(const bf16x8*)(hrow);
    bf16x8 h1 = *(const bf16x8*)(hrow + 8);
    *(bf16x8*)&frag[0][sq][sd >> 5][(sd & 31)][0]      = h0;
    *(bf16x8*)&frag[0][sq][sd >> 5][(sd & 31) + 32][0] = h1;
    __syncthreads();

    floatx16 acc0 = {0,0,0,0,0,0,0,0,0,0,0,0,0,0,0,0};
    floatx16 acc1 = {0,0,0,0,0,0,0,0,0,0,0,0,0,0,0,0};
    float zacc = 0.f;

    for (int mt = 0; mt < 16; ++mt) {
        const int cur = mt & 1;
        if (mt < 15) {                                   // prefetch next 64-k window
            h0 = *(const bf16x8*)(hrow + (mt + 1) * 64);
            h1 = *(const bf16x8*)(hrow + (mt + 1) * 64 + 8);
        }
#pragma unroll
        for (int ks = 0; ks < 4; ++ks) {
            const int mbase = mt * 64 + ks * 16 + hi * 8;
            const unsigned wb = bitsS[(mbase >> 5) * 128 + rloc] >> (mbase & 31);
            float4 av  = *(const float4*)&A2s[mbase];
            float4 av2 = *(const float4*)&A2s[mbase + 4];
            float a2v[8] = {av.x, av.y, av.z, av.w, av2.x, av2.y, av2.z, av2.w};
            float o[8];
#pragma unroll
            for (int j = 0; j < 8; ++j) {
                float s = a1r + a2v[j];
                float lr = fmaxf(s, ALPHA_ * s);
                int bm = (int)(wb << (31 - j)) >> 31;        // bit j -> all-ones
                lr = __int_as_float(__float_as_int(lr) & bm); // masked -> 0
                float t = exp2fast(lr);                       // scores pre-scaled by log2e
                zacc += t; o[j] = t;
            }
            bf16x8 af = {(__bf16)o[0], (__bf16)o[1], (__bf16)o[2], (__bf16)o[3],
                         (__bf16)o[4], (__bf16)o[5], (__bf16)o[6], (__bf16)o[7]};
            bf16x8 bv0 = *(bf16x8*)&frag[cur][ks][0][L][0];
            bf16x8 bv1 = *(bf16x8*)&frag[cur][ks][1][L][0];
            acc0 = mfma32_bf16(af, bv0, acc0);
            acc1 = mfma32_bf16(af, bv1, acc1);
        }
        if (mt < 15) {
            *(bf16x8*)&frag[cur ^ 1][sq][sd >> 5][(sd & 31)][0]      = h0;
            *(bf16x8*)&frag[cur ^ 1][sq][sd >> 5][(sd & 31) + 32][0] = h1;
            __syncthreads();
        }
    }

    // z per row: lane covers half the k's of row rloc; partner is lane^32
    zacc += __shfl_xor(zacc, 32);
    if (hi == 0) invzS[rloc] = 1.f / zacc;
    __syncthreads();      // also drains last MFMA's frag reads before ts reuse

    float iz[16];
#pragma unroll
    for (int r = 0; r < 16; ++r)
        iz[r] = invzS[rg * 32 + (r & 3) + 8 * (r >> 2) + 4 * hi];

#pragma unroll
    for (int r = 0; r < 16; ++r) {
        const int row = rg * 32 + (r & 3) + 8 * (r >> 2) + 4 * hi;
        pool[row][lq]      = (__bf16)eluf(acc0[r] * iz[r]);
        pool[row][32 + lq] = (__bf16)eluf(acc1[r] * iz[r]);
    }
    __syncthreads();
#pragma unroll
    for (int i = 0; i < 4; ++i) {
        int cid = i * 256 + tid;
        int row = cid >> 3, c8 = (cid & 7) * 8;
        bf16x8 v = *(bf16x8*)&pool[row][c8];
        *(bf16x8*)(xc_out + ((size_t)(b * N_ + n0 + row)) * 256 + head * 64 + c8) = v;
    }
}

// ---------------------------------------------------------------------------
// attn layer 2: 32-row tiles, grid (b,1,tile)=(16,1,32).
// ts2/Ht2 double-buffered -> 1 barrier/iter; scores(mt+1) computed under
// MFMA(mt). Fully unrolled so tr[16] stays in registers. exp2 scores.
__global__ __launch_bounds__(256) void attn2_kernel(
    const float* __restrict__ A1g, const float* __restrict__ A2g,
    const __bf16* __restrict__ Htg, const unsigned* __restrict__ bitsG,
    float* __restrict__ out_f, float* __restrict__ attn_f)
{
    const int b = blockIdx.x, tile = blockIdx.z;
    const int n0 = tile * 32;
    const float* A2 = A2g + (size_t)b * N_;
    const __bf16* Hglob = Htg + (size_t)b * 64 * N_;

    __shared__ __align__(16) __bf16 ts2[2][32][72];
    __shared__ __align__(16) __bf16 Ht2[2][64][72];
    __shared__ __align__(16) float A2s[N_];
    __shared__ __align__(16) unsigned bitsS[1024];   // transposed [w32][row32]
    __shared__ float invz[32];

    const int tid = threadIdx.x;
    *(float4*)&A2s[tid * 4] = *(const float4*)(A2 + tid * 4);
    {   // src word s=tid*4+k -> row=s>>5 (=tid>>3), w=s&31
        uint4 u = *(const uint4*)(bitsG + n0 * 32 + tid * 4);
        const int row = tid >> 3, wb0 = (tid & 7) * 4;
        bitsS[(wb0+0)*32+row] = u.x; bitsS[(wb0+1)*32+row] = u.y;
        bitsS[(wb0+2)*32+row] = u.z; bitsS[(wb0+3)*32+row] = u.w;
    }

    const int r2 = tid >> 3, q2 = tid & 7;          // t-staging: row r2, 8 m's
    const float a1r = A1g[(size_t)b * N_ + n0 + r2];
    const int dr = tid >> 2, dq = tid & 3;          // Ht staging
    const int w = tid >> 6, L = tid & 63, quad = L >> 4, lo = L & 15;
    const __bf16* hrow = Hglob + (size_t)dr * N_ + dq * 16;

    floatx4 acc2[2] = {{0,0,0,0},{0,0,0,0}};
    float zacc = 0.f;
    bf16x8 tr[16];

    __syncthreads();   // A2s/bitsS visible before scores(0)

    auto scores = [&](int mt) -> bf16x8 {
        const int mb = mt * 64 + q2 * 8;
        const unsigned wb = bitsS[(mt * 2 + (q2 >> 2)) * 32 + r2] >> ((q2 & 3) * 8);
        float4 alo = *(const float4*)&A2s[mb];
        float4 ahi = *(const float4*)&A2s[mb + 4];
        float a2v[8] = {alo.x, alo.y, alo.z, alo.w, ahi.x, ahi.y, ahi.z, ahi.w};
        float o[8];
#pragma unroll
        for (int j = 0; j < 8; ++j) {
            float s = a1r + a2v[j];
            float lr = fmaxf(s, ALPHA_ * s);
            int bm = (int)(wb << (31 - j)) >> 31;
            lr = __int_as_float(__float_as_int(lr) & bm);
            float t = exp2fast(lr);
            zacc += t; o[j] = t;
        }
        bf16x8 pk = {(__bf16)o[0], (__bf16)o[1], (__bf16)o[2], (__bf16)o[3],
                     (__bf16)o[4], (__bf16)o[5], (__bf16)o[6], (__bf16)o[7]};
        return pk;
    };

    {   // prologue: stage mt=0
        bf16x8 h0 = *(const bf16x8*)(hrow);
        bf16x8 h1 = *(const bf16x8*)(hrow + 8);
        bf16x8 pk = scores(0);
        tr[0] = pk;
        *(bf16x8*)&ts2[0][r2][q2 * 8]      = pk;
        *(bf16x8*)&Ht2[0][dr][dq * 16]     = h0;
        *(bf16x8*)&Ht2[0][dr][dq * 16 + 8] = h1;
    }
    __syncthreads();

#pragma unroll
    for (int mt = 0; mt < 16; ++mt) {
        const int cur = mt & 1;
        bf16x8 h0, h1, pk;
        if (mt < 15) {
            h0 = *(const bf16x8*)(hrow + (mt + 1) * 64);
            h1 = *(const bf16x8*)(hrow + (mt + 1) * 64 + 8);
            pk = scores(mt + 1);
            tr[mt + 1] = pk;
        }
#pragma unroll
        for (int c = 0; c < 2; ++c)
#pragma unroll
            for (int rt = 0; rt < 2; ++rt) {
                bf16x8 af = *(bf16x8*)&ts2[cur][16 * rt + lo][c * 32 + quad * 8];
                bf16x8 bv = *(bf16x8*)&Ht2[cur][16 * w + lo][c * 32 + quad * 8];
                acc2[rt] = mfma_bf16(af, bv, acc2[rt]);
            }
        if (mt < 15) {
            *(bf16x8*)&ts2[cur ^ 1][r2][q2 * 8]      = pk;
            *(bf16x8*)&Ht2[cur ^ 1][dr][dq * 16]     = h0;
            *(bf16x8*)&Ht2[cur ^ 1][dr][dq * 16 + 8] = h1;
            __syncthreads();
        }
    }

    zacc += __shfl_xor(zacc, 1);
    zacc += __shfl_xor(zacc, 2);
    zacc += __shfl_xor(zacc, 4);
    if (q2 == 0) invz[r2] = 1.f / zacc;
    __syncthreads();

    // out = elu(acc*invz): wave w owns d cols 16w+lo; rows rt*16+quad*4+i
#pragma unroll
    for (int rt = 0; rt < 2; ++rt)
#pragma unroll
        for (int i = 0; i < 4; ++i) {
            const int n = 16 * rt + quad * 4 + i;
            out_f[((size_t)(b * N_ + n0 + n)) * 64 + 16 * w + lo] =
                eluf(acc2[rt][i] * invz[n]);
        }

    // attn tail from saved t regs
    const float iz = invz[r2];
    float* arow = attn_f + ((size_t)(b * N_ + n0 + r2)) * N_ + q2 * 8;
#pragma unroll
    for (int mt = 0; mt < 16; ++mt) {
        bf16x8 t8 = tr[mt];
        float4 f0 = make_float4((float)t8[0] * iz, (float)t8[1] * iz,
                                (float)t8[2] * iz, (float)t8[3] * iz);
        float4 f1 = make_float4((float)t8[4] * iz, (float)t8[5] * iz,
                                (float)t8[6] * iz, (float)t8[7] * iz);
        *(float4*)(arow + mt * 64)     = f0;
        *(float4*)(arow + mt * 64 + 4) = f1;
    }
}

// ---------------------------------------------------------------------------
// proj2: h2 = xc_bf16 @ (n0<512 ? W1o : W2o) via MFMA (K=256); ao-dots + h2t out.
__global__ __launch_bounds__(256) void proj2_kernel(
    const __bf16* __restrict__ xcb, const float* __restrict__ W1o,
    const float* __restrict__ W2o, const float* __restrict__ ao,
    __bf16* __restrict__ h2t, float* __restrict__ A1o, float* __restrict__ A2o)
{
    const int tile = blockIdx.x, b = blockIdx.y;
    const int n0 = tile * 64;
    const float* W = (n0 < 512) ? W1o : W2o;

    __shared__ __align__(16) __bf16 xs[64][264];
    __shared__ __align__(16) __bf16 Wt[64][264];
    __shared__ __align__(16) float as_[128];

    const int tid = threadIdx.x;
    if (tid < 128) as_[tid] = ao[tid];

#pragma unroll
    for (int i = 0; i < 8; ++i) {
        int idx = i * 256 + tid;
        int row = idx >> 5, c = (idx & 31) * 8;
        *(bf16x8*)&xs[row][c] =
            *(const bf16x8*)(xcb + ((size_t)(b * N_ + n0 + row)) * 256 + c);
    }
#pragma unroll
    for (int i = 0; i < 16; ++i) {
        int idx = i * 256 + tid;
        int k = idx >> 4, n4 = (idx & 15) * 4;
        float4 wv = *(const float4*)(W + (size_t)k * 64 + n4);
        Wt[n4 + 0][k] = (__bf16)wv.x;
        Wt[n4 + 1][k] = (__bf16)wv.y;
        Wt[n4 + 2][k] = (__bf16)wv.z;
        Wt[n4 + 3][k] = (__bf16)wv.w;
    }
    __syncthreads();

    const int w = tid >> 6, L = tid & 63, quad = L >> 4, lo = L & 15;
    floatx4 acc[4] = {{0,0,0,0},{0,0,0,0},{0,0,0,0},{0,0,0,0}};
#pragma unroll
    for (int kc = 0; kc < 8; ++kc) {
        bf16x8 af = *(bf16x8*)&xs[16 * w + lo][kc * 32 + quad * 8];
#pragma unroll
        for (int t = 0; t < 4; ++t) {
            bf16x8 bv = *(bf16x8*)&Wt[16 * t + lo][kc * 32 + quad * 8];
            acc[t] = mfma_bf16(af, bv, acc[t]);
        }
    }

    float p1[4] = {0, 0, 0, 0}, p2[4] = {0, 0, 0, 0};
#pragma unroll
    for (int t = 0; t < 4; ++t) {
        float a1w = as_[16 * t + lo], a2w = as_[64 + 16 * t + lo];
#pragma unroll
        for (int i = 0; i < 4; ++i) { p1[i] += acc[t][i] * a1w; p2[i] += acc[t][i] * a2w; }
    }
#pragma unroll
    for (int s = 1; s < 16; s <<= 1)
#pragma unroll
        for (int i = 0; i < 4; ++i) {
            p1[i] += __shfl_xor(p1[i], s);
            p2[i] += __shfl_xor(p2[i], s);
        }
    if (lo == 0) {
#pragma unroll
        for (int i = 0; i < 4; ++i) {
            int n = 16 * w + quad * 4 + i;
            A1o[b * N_ + n0 + n] = p1[i] * LOG2E_;
            A2o[b * N_ + n0 + n] = p2[i] * LOG2E_;
        }
    }

    __syncthreads();
#pragma unroll
    for (int t = 0; t < 4; ++t)
#pragma unroll
        for (int i = 0; i < 4; ++i)
            xs[16 * w + quad * 4 + i][16 * t + lo] = (__bf16)acc[t][i];
    __syncthreads();
    const int d = tid & 63, ch = tid >> 6;
    bf16x8 v0, v1;
#pragma unroll
    for (int j = 0; j < 8; ++j) v0[j] = xs[ch * 16 + j][d];
#pragma unroll
    for (int j = 0; j < 8; ++j) v1[j] = xs[ch * 16 + 8 + j][d];
    bf16x8* dst = (bf16x8*)(h2t + ((size_t)b * 64 + d) * N_ + n0 + ch * 16);
    dst[0] = v0; dst[1] = v1;
}

// ---------------------------------------------------------------------------
extern "C" void kernel_launch(void* const* d_in, const int* in_sizes, int n_in,
                              void* d_out, int out_size, void* d_ws, size_t ws_size,
                              hipStream_t stream)
{
    const float* x    = (const float*)d_in[0];
    const float* mask = (const float*)d_in[1];
    const float* W1   = (const float*)d_in[2];
    const float* W2   = (const float*)d_in[3];
    const float* a    = (const float*)d_in[4];
    const float* W1o  = (const float*)d_in[5];
    const float* W2o  = (const float*)d_in[6];
    const float* ao   = (const float*)d_in[7];

    float* out      = (float*)d_out;                 // [16,1024,64] fp32
    float* attn_out = out + (size_t)B_ * N_ * 64;    // [16,1024,1024] fp32

    float*    ws    = (float*)d_ws;
    float*    A1    = ws;                       // 65536 f
    float*    A2    = A1 + 65536;               // 65536 f
    float*    A1o   = A2 + 65536;               // 16384 f
    float*    A2o   = A1o + 16384;              // 16384 f
    __bf16*   h1t   = (__bf16*)(A2o + 16384);   // 4*16*64*1024 bf16
    __bf16*   h2t   = h1t + 4194304;            // 16*64*1024 bf16
    __bf16*   xcb   = h2t + 1048576;            // 16*1024*256 bf16
    unsigned* bitsG = (unsigned*)(xcb + 4194304); // 32768 u32

    proj1_kernel<<<dim3(16, 16, 4), 256, 0, stream>>>(x, W1, W2, a, mask, bitsG,
                                                      h1t, A1, A2);
    attn1_kernel<<<dim3(16, 4, 8), 256, 0, stream>>>(A1, A2, h1t, bitsG, xcb);
    proj2_kernel<<<dim3(16, 16, 1), 256, 0, stream>>>(xcb, W1o, W2o, ao, h2t, A1o, A2o);
    attn2_kernel<<<dim3(16, 1, 32), 256, 0, stream>>>(A1o, A2o, h2t, bitsG, out, attn_out);
}

// Round 8
// 149.869 us; speedup vs baseline: 1.0875x; 1.0209x over previous
//
#include <hip/hip_runtime.h>
#include <hip/hip_bf16.h>

#define B_      16
#define N_      1024
#define ALPHA_  0.2f
#define LOG2E_  1.4426950408889634f

typedef __attribute__((ext_vector_type(8)))  __bf16 bf16x8;
typedef __attribute__((ext_vector_type(4)))  float  floatx4;
typedef __attribute__((ext_vector_type(16))) float  floatx16;

__device__ __forceinline__ float eluf(float u) { return u > 0.f ? u : __expf(u) - 1.f; }

__device__ __forceinline__ float exp2fast(float x) {
#if __has_builtin(__builtin_amdgcn_exp2f)
    return __builtin_amdgcn_exp2f(x);
#else
    return exp2f(x);
#endif
}

__device__ __forceinline__ floatx4 mfma_bf16(bf16x8 a, bf16x8 b, floatx4 c) {
    return __builtin_amdgcn_mfma_f32_16x16x32_bf16(a, b, c, 0, 0, 0);
}
__device__ __forceinline__ floatx16 mfma32_bf16(bf16x8 a, bf16x8 b, floatx16 c) {
    return __builtin_amdgcn_mfma_f32_32x32x16_bf16(a, b, c, 0, 0, 0);
}

// ---------------------------------------------------------------------------
// proj1 (MFMA): h = x[b,n0:n0+64,:64] @ (n0<512 ? W1[head] : W2[head])
// writes h1t[(head*16+b)*64 + d][m] bf16 (transposed) + A1/A2 fp32 dots
// (pre-scaled by log2e for exp2 consumers). Also folds maskbits conversion.
// grid (16,16,4) = 1024 blocks -> 4 blocks/CU latency hiding.
__global__ __launch_bounds__(256) void proj1_kernel(
    const float* __restrict__ x, const float* __restrict__ W1,
    const float* __restrict__ W2, const float* __restrict__ av,
    const float* __restrict__ maskG, unsigned* __restrict__ bitsOut,
    __bf16* __restrict__ h1t, float* __restrict__ A1, float* __restrict__ A2)
{
    const int tile = blockIdx.x, b = blockIdx.y, head = blockIdx.z;
    const int n0 = tile * 64;
    const float* W  = ((n0 < 512) ? W1 : W2) + head * 64 * 64;
    const float* ah = av + head * 128;

    __shared__ __align__(16) __bf16 xs[64][72];
    __shared__ __align__(16) __bf16 Wt[64][72];
    __shared__ __align__(16) float as_[128];

    const int tid = threadIdx.x;
    if (tid < 128) as_[tid] = ah[tid];
#pragma unroll
    for (int i = 0; i < 4; ++i) {
        int idx = i * 256 + tid;
        int r = idx >> 4, c = (idx & 15) * 4;
        float4 v = *(const float4*)(x + ((size_t)(b * N_ + n0 + r)) * 64 + c);
        xs[r][c+0] = (__bf16)v.x; xs[r][c+1] = (__bf16)v.y;
        xs[r][c+2] = (__bf16)v.z; xs[r][c+3] = (__bf16)v.w;
        float4 wv = *(const float4*)(W + (size_t)r * 64 + c);
        Wt[c+0][r] = (__bf16)wv.x; Wt[c+1][r] = (__bf16)wv.y;
        Wt[c+2][r] = (__bf16)wv.z; Wt[c+3][r] = (__bf16)wv.w;
    }

    // fused maskbits: this block converts its 32 words (1024 mask floats)
    {
        const int bid = blockIdx.x + 16 * (blockIdx.y + 16 * blockIdx.z);
        if (tid < 32) {
            const float* src = maskG + ((size_t)(bid * 32 + tid)) * 32;
            unsigned v = 0;
#pragma unroll
            for (int j = 0; j < 8; ++j) {
                float4 f = *(const float4*)(src + j * 4);
                v |= ((unsigned)(f.x != 0.f)) << (j * 4 + 0);
                v |= ((unsigned)(f.y != 0.f)) << (j * 4 + 1);
                v |= ((unsigned)(f.z != 0.f)) << (j * 4 + 2);
                v |= ((unsigned)(f.w != 0.f)) << (j * 4 + 3);
            }
            bitsOut[bid * 32 + tid] = v;
        }
    }
    __syncthreads();

    const int w = tid >> 6, L = tid & 63, quad = L >> 4, lo = L & 15;
    floatx4 acc[4] = {{0,0,0,0},{0,0,0,0},{0,0,0,0},{0,0,0,0}};
#pragma unroll
    for (int kc = 0; kc < 2; ++kc) {
        bf16x8 af = *(bf16x8*)&xs[16 * w + lo][kc * 32 + quad * 8];
#pragma unroll
        for (int t = 0; t < 4; ++t) {
            bf16x8 bv = *(bf16x8*)&Wt[16 * t + lo][kc * 32 + quad * 8];
            acc[t] = mfma_bf16(af, bv, acc[t]);
        }
    }

    float p1[4] = {0, 0, 0, 0}, p2[4] = {0, 0, 0, 0};
#pragma unroll
    for (int t = 0; t < 4; ++t) {
        float a1w = as_[16 * t + lo], a2w = as_[64 + 16 * t + lo];
#pragma unroll
        for (int i = 0; i < 4; ++i) { p1[i] += acc[t][i] * a1w; p2[i] += acc[t][i] * a2w; }
    }
#pragma unroll
    for (int s = 1; s < 16; s <<= 1)
#pragma unroll
        for (int i = 0; i < 4; ++i) {
            p1[i] += __shfl_xor(p1[i], s);
            p2[i] += __shfl_xor(p2[i], s);
        }
    const int bh = head * B_ + b;
    if (lo == 0) {
#pragma unroll
        for (int i = 0; i < 4; ++i) {
            int n = 16 * w + quad * 4 + i;
            A1[bh * N_ + n0 + n] = p1[i] * LOG2E_;
            A2[bh * N_ + n0 + n] = p2[i] * LOG2E_;
        }
    }

    __syncthreads();
#pragma unroll
    for (int t = 0; t < 4; ++t)
#pragma unroll
        for (int i = 0; i < 4; ++i)
            xs[16 * w + quad * 4 + i][16 * t + lo] = (__bf16)acc[t][i];
    __syncthreads();
    const int d = tid & 63, ch = tid >> 6;
    bf16x8 v0, v1;
#pragma unroll
    for (int j = 0; j < 8; ++j) v0[j] = xs[ch * 16 + j][d];
#pragma unroll
    for (int j = 0; j < 8; ++j) v1[j] = xs[ch * 16 + 8 + j][d];
    bf16x8* dst = (bf16x8*)(h1t + ((size_t)bh * 64 + d) * N_ + n0 + ch * 16);
    dst[0] = v0; dst[1] = v1;
}

// ---------------------------------------------------------------------------
// attn layer 1 (32x32x16 MFMA): grid (b, head, tile) = (16,4,8), 128-row tiles.
// P computed directly in the 32x32 A-fragment layout in registers (zero LDS
// for P). H^T staged PRE-FRAGMENTED in LDS (coalesced global reads ->
// conflict-free ds_read_b128 at base+lane*16). frag and ts kept as SEPARATE
// arrays: aliasing them (r5/r7) costs ~3us via pessimized LDS scheduling.
__global__ __launch_bounds__(256) void attn1_kernel(
    const float* __restrict__ A1g, const float* __restrict__ A2g,
    const __bf16* __restrict__ Htg, const unsigned* __restrict__ bitsG,
    __bf16* __restrict__ xc_out)
{
    const int b = blockIdx.x, head = blockIdx.y, tile = blockIdx.z;
    const int n0 = tile * 128;
    const int bh = head * B_ + b;
    const float* A2 = A2g + (size_t)bh * N_;
    const __bf16* Hglob = Htg + (size_t)bh * 64 * N_;

    __shared__ __align__(16) __bf16 frag[2][4][2][64][8]; // [buf][ks][dt][lane][j]
    __shared__ __align__(16) __bf16 ts[128][72];
    __shared__ __align__(16) float A2s[N_];
    __shared__ __align__(16) unsigned bitsS[32 * 128];    // [w][row]
    __shared__ float invzS[128];

    const int tid = threadIdx.x;
    *(float4*)&A2s[tid * 4] = *(const float4*)(A2 + tid * 4);
    {   // bits rows n0..n0+127 transposed: src word s=tid*16+k -> row=tid>>1, w=(tid&1)*16+k
        const int row = tid >> 1, w0 = (tid & 1) * 16;
        uint4 u0 = *(const uint4*)(bitsG + n0 * 32 + tid * 16);
        uint4 u1 = *(const uint4*)(bitsG + n0 * 32 + tid * 16 + 4);
        uint4 u2 = *(const uint4*)(bitsG + n0 * 32 + tid * 16 + 8);
        uint4 u3 = *(const uint4*)(bitsG + n0 * 32 + tid * 16 + 12);
        bitsS[(w0+ 0)*128+row] = u0.x; bitsS[(w0+ 1)*128+row] = u0.y;
        bitsS[(w0+ 2)*128+row] = u0.z; bitsS[(w0+ 3)*128+row] = u0.w;
        bitsS[(w0+ 4)*128+row] = u1.x; bitsS[(w0+ 5)*128+row] = u1.y;
        bitsS[(w0+ 6)*128+row] = u1.z; bitsS[(w0+ 7)*128+row] = u1.w;
        bitsS[(w0+ 8)*128+row] = u2.x; bitsS[(w0+ 9)*128+row] = u2.y;
        bitsS[(w0+10)*128+row] = u2.z; bitsS[(w0+11)*128+row] = u2.w;
        bitsS[(w0+12)*128+row] = u3.x; bitsS[(w0+13)*128+row] = u3.y;
        bitsS[(w0+14)*128+row] = u3.z; bitsS[(w0+15)*128+row] = u3.w;
    }

    const int sd = tid >> 2, sq = tid & 3;               // staging: row d, 16-k window
    const __bf16* hrow = Hglob + (size_t)sd * N_ + sq * 16;
    const int L = tid & 63, rg = tid >> 6, hi = L >> 5, lq = L & 31;
    const int rloc = rg * 32 + lq;                       // this lane's P-row (block-local)
    const float a1r = A1g[(size_t)bh * N_ + n0 + rloc];

    // prologue: stage mt=0 (barrier also covers A2s/bitsS)
    bf16x8 h0 = *(const bf16x8*)(hrow);
    bf16x8 h1 = *(const bf16x8*)(hrow + 8);
    *(bf16x8*)&frag[0][sq][sd >> 5][(sd & 31)][0]      = h0;
    *(bf16x8*)&frag[0][sq][sd >> 5][(sd & 31) + 32][0] = h1;
    __syncthreads();

    floatx16 acc0 = {0,0,0,0,0,0,0,0,0,0,0,0,0,0,0,0};
    floatx16 acc1 = {0,0,0,0,0,0,0,0,0,0,0,0,0,0,0,0};
    float zacc = 0.f;

    for (int mt = 0; mt < 16; ++mt) {
        const int cur = mt & 1;
        if (mt < 15) {                                   // prefetch next 64-k window
            h0 = *(const bf16x8*)(hrow + (mt + 1) * 64);
            h1 = *(const bf16x8*)(hrow + (mt + 1) * 64 + 8);
        }
#pragma unroll
        for (int ks = 0; ks < 4; ++ks) {
            const int mbase = mt * 64 + ks * 16 + hi * 8;
            const unsigned wb = bitsS[(mbase >> 5) * 128 + rloc] >> (mbase & 31);
            float4 av  = *(const float4*)&A2s[mbase];
            float4 av2 = *(const float4*)&A2s[mbase + 4];
            float a2v[8] = {av.x, av.y, av.z, av.w, av2.x, av2.y, av2.z, av2.w};
            float o[8];
#pragma unroll
            for (int j = 0; j < 8; ++j) {
                float s = a1r + a2v[j];
                float lr = fmaxf(s, ALPHA_ * s);
                int bm = (int)(wb << (31 - j)) >> 31;        // bit j -> all-ones
                lr = __int_as_float(__float_as_int(lr) & bm); // masked -> 0
                float t = exp2fast(lr);                       // scores pre-scaled by log2e
                zacc += t; o[j] = t;
            }
            bf16x8 af = {(__bf16)o[0], (__bf16)o[1], (__bf16)o[2], (__bf16)o[3],
                         (__bf16)o[4], (__bf16)o[5], (__bf16)o[6], (__bf16)o[7]};
            bf16x8 bv0 = *(bf16x8*)&frag[cur][ks][0][L][0];
            bf16x8 bv1 = *(bf16x8*)&frag[cur][ks][1][L][0];
            acc0 = mfma32_bf16(af, bv0, acc0);
            acc1 = mfma32_bf16(af, bv1, acc1);
        }
        if (mt < 15) {
            *(bf16x8*)&frag[cur ^ 1][sq][sd >> 5][(sd & 31)][0]      = h0;
            *(bf16x8*)&frag[cur ^ 1][sq][sd >> 5][(sd & 31) + 32][0] = h1;
            __syncthreads();
        }
    }

    // z per row: lane covers half the k's of row rloc; partner is lane^32
    zacc += __shfl_xor(zacc, 32);
    if (hi == 0) invzS[rloc] = 1.f / zacc;
    __syncthreads();

    float iz[16];
#pragma unroll
    for (int r = 0; r < 16; ++r)
        iz[r] = invzS[rg * 32 + (r & 3) + 8 * (r >> 2) + 4 * hi];

#pragma unroll
    for (int r = 0; r < 16; ++r) {
        const int row = rg * 32 + (r & 3) + 8 * (r >> 2) + 4 * hi;
        ts[row][lq]      = (__bf16)eluf(acc0[r] * iz[r]);
        ts[row][32 + lq] = (__bf16)eluf(acc1[r] * iz[r]);
    }
    __syncthreads();
#pragma unroll
    for (int i = 0; i < 4; ++i) {
        int cid = i * 256 + tid;
        int row = cid >> 3, c8 = (cid & 7) * 8;
        bf16x8 v = *(bf16x8*)&ts[row][c8];
        *(bf16x8*)(xc_out + ((size_t)(b * N_ + n0 + row)) * 256 + head * 64 + c8) = v;
    }
}

// ---------------------------------------------------------------------------
// attn layer 2: 32-row tiles, grid (b,1,tile)=(16,1,32).
// ts2/Ht2 double-buffered -> 1 barrier/iter; scores(mt+1) computed under
// MFMA(mt). Fully unrolled so tr[16] stays in registers. exp2 scores.
__global__ __launch_bounds__(256) void attn2_kernel(
    const float* __restrict__ A1g, const float* __restrict__ A2g,
    const __bf16* __restrict__ Htg, const unsigned* __restrict__ bitsG,
    float* __restrict__ out_f, float* __restrict__ attn_f)
{
    const int b = blockIdx.x, tile = blockIdx.z;
    const int n0 = tile * 32;
    const float* A2 = A2g + (size_t)b * N_;
    const __bf16* Hglob = Htg + (size_t)b * 64 * N_;

    __shared__ __align__(16) __bf16 ts2[2][32][72];
    __shared__ __align__(16) __bf16 Ht2[2][64][72];
    __shared__ __align__(16) float A2s[N_];
    __shared__ __align__(16) unsigned bitsS[1024];   // transposed [w32][row32]
    __shared__ float invz[32];

    const int tid = threadIdx.x;
    *(float4*)&A2s[tid * 4] = *(const float4*)(A2 + tid * 4);
    {   // src word s=tid*4+k -> row=s>>5 (=tid>>3), w=s&31
        uint4 u = *(const uint4*)(bitsG + n0 * 32 + tid * 4);
        const int row = tid >> 3, wb0 = (tid & 7) * 4;
        bitsS[(wb0+0)*32+row] = u.x; bitsS[(wb0+1)*32+row] = u.y;
        bitsS[(wb0+2)*32+row] = u.z; bitsS[(wb0+3)*32+row] = u.w;
    }

    const int r2 = tid >> 3, q2 = tid & 7;          // t-staging: row r2, 8 m's
    const float a1r = A1g[(size_t)b * N_ + n0 + r2];
    const int dr = tid >> 2, dq = tid & 3;          // Ht staging
    const int w = tid >> 6, L = tid & 63, quad = L >> 4, lo = L & 15;
    const __bf16* hrow = Hglob + (size_t)dr * N_ + dq * 16;

    floatx4 acc2[2] = {{0,0,0,0},{0,0,0,0}};
    float zacc = 0.f;
    bf16x8 tr[16];

    __syncthreads();   // A2s/bitsS visible before scores(0)

    auto scores = [&](int mt) -> bf16x8 {
        const int mb = mt * 64 + q2 * 8;
        const unsigned wb = bitsS[(mt * 2 + (q2 >> 2)) * 32 + r2] >> ((q2 & 3) * 8);
        float4 alo = *(const float4*)&A2s[mb];
        float4 ahi = *(const float4*)&A2s[mb + 4];
        float a2v[8] = {alo.x, alo.y, alo.z, alo.w, ahi.x, ahi.y, ahi.z, ahi.w};
        float o[8];
#pragma unroll
        for (int j = 0; j < 8; ++j) {
            float s = a1r + a2v[j];
            float lr = fmaxf(s, ALPHA_ * s);
            int bm = (int)(wb << (31 - j)) >> 31;
            lr = __int_as_float(__float_as_int(lr) & bm);
            float t = exp2fast(lr);
            zacc += t; o[j] = t;
        }
        bf16x8 pk = {(__bf16)o[0], (__bf16)o[1], (__bf16)o[2], (__bf16)o[3],
                     (__bf16)o[4], (__bf16)o[5], (__bf16)o[6], (__bf16)o[7]};
        return pk;
    };

    {   // prologue: stage mt=0
        bf16x8 h0 = *(const bf16x8*)(hrow);
        bf16x8 h1 = *(const bf16x8*)(hrow + 8);
        bf16x8 pk = scores(0);
        tr[0] = pk;
        *(bf16x8*)&ts2[0][r2][q2 * 8]      = pk;
        *(bf16x8*)&Ht2[0][dr][dq * 16]     = h0;
        *(bf16x8*)&Ht2[0][dr][dq * 16 + 8] = h1;
    }
    __syncthreads();

#pragma unroll
    for (int mt = 0; mt < 16; ++mt) {
        const int cur = mt & 1;
        bf16x8 h0, h1, pk;
        if (mt < 15) {
            h0 = *(const bf16x8*)(hrow + (mt + 1) * 64);
            h1 = *(const bf16x8*)(hrow + (mt + 1) * 64 + 8);
            pk = scores(mt + 1);
            tr[mt + 1] = pk;
        }
#pragma unroll
        for (int c = 0; c < 2; ++c)
#pragma unroll
            for (int rt = 0; rt < 2; ++rt) {
                bf16x8 af = *(bf16x8*)&ts2[cur][16 * rt + lo][c * 32 + quad * 8];
                bf16x8 bv = *(bf16x8*)&Ht2[cur][16 * w + lo][c * 32 + quad * 8];
                acc2[rt] = mfma_bf16(af, bv, acc2[rt]);
            }
        if (mt < 15) {
            *(bf16x8*)&ts2[cur ^ 1][r2][q2 * 8]      = pk;
            *(bf16x8*)&Ht2[cur ^ 1][dr][dq * 16]     = h0;
            *(bf16x8*)&Ht2[cur ^ 1][dr][dq * 16 + 8] = h1;
            __syncthreads();
        }
    }

    zacc += __shfl_xor(zacc, 1);
    zacc += __shfl_xor(zacc, 2);
    zacc += __shfl_xor(zacc, 4);
    if (q2 == 0) invz[r2] = 1.f / zacc;
    __syncthreads();

    // out = elu(acc*invz): wave w owns d cols 16w+lo; rows rt*16+quad*4+i
#pragma unroll
    for (int rt = 0; rt < 2; ++rt)
#pragma unroll
        for (int i = 0; i < 4; ++i) {
            const int n = 16 * rt + quad * 4 + i;
            out_f[((size_t)(b * N_ + n0 + n)) * 64 + 16 * w + lo] =
                eluf(acc2[rt][i] * invz[n]);
        }

    // attn tail from saved t regs
    const float iz = invz[r2];
    float* arow = attn_f + ((size_t)(b * N_ + n0 + r2)) * N_ + q2 * 8;
#pragma unroll
    for (int mt = 0; mt < 16; ++mt) {
        bf16x8 t8 = tr[mt];
        float4 f0 = make_float4((float)t8[0] * iz, (float)t8[1] * iz,
                                (float)t8[2] * iz, (float)t8[3] * iz);
        float4 f1 = make_float4((float)t8[4] * iz, (float)t8[5] * iz,
                                (float)t8[6] * iz, (float)t8[7] * iz);
        *(float4*)(arow + mt * 64)     = f0;
        *(float4*)(arow + mt * 64 + 4) = f1;
    }
}

// ---------------------------------------------------------------------------
// proj2: h2 = xc_bf16 @ (n0<512 ? W1o : W2o) via MFMA (K=256); ao-dots + h2t out.
__global__ __launch_bounds__(256) void proj2_kernel(
    const __bf16* __restrict__ xcb, const float* __restrict__ W1o,
    const float* __restrict__ W2o, const float* __restrict__ ao,
    __bf16* __restrict__ h2t, float* __restrict__ A1o, float* __restrict__ A2o)
{
    const int tile = blockIdx.x, b = blockIdx.y;
    const int n0 = tile * 64;
    const float* W = (n0 < 512) ? W1o : W2o;

    __shared__ __align__(16) __bf16 xs[64][264];
    __shared__ __align__(16) __bf16 Wt[64][264];
    __shared__ __align__(16) float as_[128];

    const int tid = threadIdx.x;
    if (tid < 128) as_[tid] = ao[tid];

#pragma unroll
    for (int i = 0; i < 8; ++i) {
        int idx = i * 256 + tid;
        int row = idx >> 5, c = (idx & 31) * 8;
        *(bf16x8*)&xs[row][c] =
            *(const bf16x8*)(xcb + ((size_t)(b * N_ + n0 + row)) * 256 + c);
    }
#pragma unroll
    for (int i = 0; i < 16; ++i) {
        int idx = i * 256 + tid;
        int k = idx >> 4, n4 = (idx & 15) * 4;
        float4 wv = *(const float4*)(W + (size_t)k * 64 + n4);
        Wt[n4 + 0][k] = (__bf16)wv.x;
        Wt[n4 + 1][k] = (__bf16)wv.y;
        Wt[n4 + 2][k] = (__bf16)wv.z;
        Wt[n4 + 3][k] = (__bf16)wv.w;
    }
    __syncthreads();

    const int w = tid >> 6, L = tid & 63, quad = L >> 4, lo = L & 15;
    floatx4 acc[4] = {{0,0,0,0},{0,0,0,0},{0,0,0,0},{0,0,0,0}};
#pragma unroll
    for (int kc = 0; kc < 8; ++kc) {
        bf16x8 af = *(bf16x8*)&xs[16 * w + lo][kc * 32 + quad * 8];
#pragma unroll
        for (int t = 0; t < 4; ++t) {
            bf16x8 bv = *(bf16x8*)&Wt[16 * t + lo][kc * 32 + quad * 8];
            acc[t] = mfma_bf16(af, bv, acc[t]);
        }
    }

    float p1[4] = {0, 0, 0, 0}, p2[4] = {0, 0, 0, 0};
#pragma unroll
    for (int t = 0; t < 4; ++t) {
        float a1w = as_[16 * t + lo], a2w = as_[64 + 16 * t + lo];
#pragma unroll
        for (int i = 0; i < 4; ++i) { p1[i] += acc[t][i] * a1w; p2[i] += acc[t][i] * a2w; }
    }
#pragma unroll
    for (int s = 1; s < 16; s <<= 1)
#pragma unroll
        for (int i = 0; i < 4; ++i) {
            p1[i] += __shfl_xor(p1[i], s);
            p2[i] += __shfl_xor(p2[i], s);
        }
    if (lo == 0) {
#pragma unroll
        for (int i = 0; i < 4; ++i) {
            int n = 16 * w + quad * 4 + i;
            A1o[b * N_ + n0 + n] = p1[i] * LOG2E_;
            A2o[b * N_ + n0 + n] = p2[i] * LOG2E_;
        }
    }

    __syncthreads();
#pragma unroll
    for (int t = 0; t < 4; ++t)
#pragma unroll
        for (int i = 0; i < 4; ++i)
            xs[16 * w + quad * 4 + i][16 * t + lo] = (__bf16)acc[t][i];
    __syncthreads();
    const int d = tid & 63, ch = tid >> 6;
    bf16x8 v0, v1;
#pragma unroll
    for (int j = 0; j < 8; ++j) v0[j] = xs[ch * 16 + j][d];
#pragma unroll
    for (int j = 0; j < 8; ++j) v1[j] = xs[ch * 16 + 8 + j][d];
    bf16x8* dst = (bf16x8*)(h2t + ((size_t)b * 64 + d) * N_ + n0 + ch * 16);
    dst[0] = v0; dst[1] = v1;
}

// ---------------------------------------------------------------------------
extern "C" void kernel_launch(void* const* d_in, const int* in_sizes, int n_in,
                              void* d_out, int out_size, void* d_ws, size_t ws_size,
                              hipStream_t stream)
{
    const float* x    = (const float*)d_in[0];
    const float* mask = (const float*)d_in[1];
    const float* W1   = (const float*)d_in[2];
    const float* W2   = (const float*)d_in[3];
    const float* a    = (const float*)d_in[4];
    const float* W1o  = (const float*)d_in[5];
    const float* W2o  = (const float*)d_in[6];
    const float* ao   = (const float*)d_in[7];

    float* out      = (float*)d_out;                 // [16,1024,64] fp32
    float* attn_out = out + (size_t)B_ * N_ * 64;    // [16,1024,1024] fp32

    float*    ws    = (float*)d_ws;
    float*    A1    = ws;                       // 65536 f
    float*    A2    = A1 + 65536;               // 65536 f
    float*    A1o   = A2 + 65536;               // 16384 f
    float*    A2o   = A1o + 16384;              // 16384 f
    __bf16*   h1t   = (__bf16*)(A2o + 16384);   // 4*16*64*1024 bf16
    __bf16*   h2t   = h1t + 4194304;            // 16*64*1024 bf16
    __bf16*   xcb   = h2t + 1048576;            // 16*1024*256 bf16
    unsigned* bitsG = (unsigned*)(xcb + 4194304); // 32768 u32

    proj1_kernel<<<dim3(16, 16, 4), 256, 0, stream>>>(x, W1, W2, a, mask, bitsG,
                                                      h1t, A1, A2);
    attn1_kernel<<<dim3(16, 4, 8), 256, 0, stream>>>(A1, A2, h1t, bitsG, xcb);
    proj2_kernel<<<dim3(16, 16, 1), 256, 0, stream>>>(xcb, W1o, W2o, ao, h2t, A1o, A2o);
    attn2_kernel<<<dim3(16, 1, 32), 256, 0, stream>>>(A1o, A2o, h2t, bitsG, out, attn_out);
}